// Round 2
// baseline (261.049 us; speedup 1.0000x reference)
//
#include <hip/hip_runtime.h>
#include <math.h>

#define NROWS 131072
#define M 8
#define D 128
#define E_CONST 2.71828182845904523536f

// ---------------------------------------------------------------------------
// Kernel A: compute betas[n,m] for all rows. One row per thread.
// ---------------------------------------------------------------------------
__global__ __launch_bounds__(256) void emma_beta_kernel(
    const float* __restrict__ q,
    const float* __restrict__ w, const float* __restrict__ b,
    const float* __restrict__ gammas, const float* __restrict__ G,
    const float* __restrict__ bias, const float* __restrict__ qmin,
    float* __restrict__ betas)
{
    const int n = blockIdx.x * 256 + threadIdx.x;
    if (n >= NROWS) return;

    const float4 q0 = *reinterpret_cast<const float4*>(q + (size_t)n * M);
    const float4 q1 = *reinterpret_cast<const float4*>(q + (size_t)n * M + 4);
    float qv[M] = {q0.x, q0.y, q0.z, q0.w, q1.x, q1.y, q1.z, q1.w};

    float lphi[M];
    #pragma unroll
    for (int m = 0; m < M; ++m) {
        float corr = fmaxf(qv[m] - qmin[m] + E_CONST, E_CONST);
        float phi  = (1.0f + w[m]) * corr + b[m];
        lphi[m] = logf(phi);   // phi >= e > 0 always
    }

    // modal[i] = sum_j phi_i^g * phi_j^(1-g) = sum_j exp(g*(lphi_i-lphi_j) + lphi_j)
    float modal[M];
    #pragma unroll
    for (int i = 0; i < M; ++i) {
        float s = 0.0f;
        #pragma unroll
        for (int j = 0; j < M; ++j) {
            float g = (i < j) ? gammas[i * M + j] : gammas[j * M + i];
            s += expf(fmaf(g, lphi[i] - lphi[j], lphi[j]));
        }
        modal[i] = s;
    }

    // alphas = softmax(-modal)  (TAU = 1)
    float mx = -modal[0];
    #pragma unroll
    for (int i = 1; i < M; ++i) mx = fmaxf(mx, -modal[i]);
    float esum = 0.0f;
    float ea[M];
    #pragma unroll
    for (int i = 0; i < M; ++i) {
        ea[i] = expf(-modal[i] - mx);
        esum += ea[i];
    }
    float inv = 1.0f / esum;

    // betas = relu(tanh(G*alpha + bias))
    float4 o0, o1;
    float bo[M];
    #pragma unroll
    for (int m = 0; m < M; ++m) {
        float alpha = ea[m] * inv;
        float t = tanhf(fmaf(G[m], alpha, bias[m]));
        bo[m] = fmaxf(t, 0.0f);
    }
    o0.x = bo[0]; o0.y = bo[1]; o0.z = bo[2]; o0.w = bo[3];
    o1.x = bo[4]; o1.y = bo[5]; o1.z = bo[6]; o1.w = bo[7];
    *reinterpret_cast<float4*>(betas + (size_t)n * M)     = o0;
    *reinterpret_cast<float4*>(betas + (size_t)n * M + 4) = o1;
}

// ---------------------------------------------------------------------------
// Kernel B: pure streaming scale-copy. out[i] = x[i] * beta[i>>5] (float4 units)
// ---------------------------------------------------------------------------
#define NV4 ((size_t)NROWS * M * D / 4)   // 33,554,432 float4s
#define SB_BLOCKS 2048

__global__ __launch_bounds__(256) void emma_scale_kernel(
    const float4* __restrict__ x4,
    const float* __restrict__ betas,
    float4* __restrict__ o4)
{
    size_t i = (size_t)blockIdx.x * 256 + threadIdx.x;
    const size_t stride = (size_t)SB_BLOCKS * 256;
    #pragma unroll 4
    for (int k = 0; k < (int)(NV4 / stride); ++k, i += stride) {
        const float bta = betas[i >> 5];
        float4 v = x4[i];
        v.x *= bta; v.y *= bta; v.z *= bta; v.w *= bta;
        o4[i] = v;
    }
}

// ---------------------------------------------------------------------------
// Fallback fused kernel (used only if ws_size < betas size)
// ---------------------------------------------------------------------------
#define ROWS_PER_BLOCK 128
__global__ __launch_bounds__(256) void emma_fused_kernel(
    const float* __restrict__ x, const float* __restrict__ q,
    const float* __restrict__ w, const float* __restrict__ b,
    const float* __restrict__ gammas, const float* __restrict__ G,
    const float* __restrict__ bias, const float* __restrict__ qmin,
    float* __restrict__ out)
{
    __shared__ float s_beta[ROWS_PER_BLOCK][M];
    const int tid = threadIdx.x;
    const int row0 = blockIdx.x * ROWS_PER_BLOCK;

    if (tid < ROWS_PER_BLOCK) {
        const int n = row0 + tid;
        const float4 q0 = *reinterpret_cast<const float4*>(q + (size_t)n * M);
        const float4 q1 = *reinterpret_cast<const float4*>(q + (size_t)n * M + 4);
        float qv[M] = {q0.x, q0.y, q0.z, q0.w, q1.x, q1.y, q1.z, q1.w};
        float lphi[M];
        #pragma unroll
        for (int m = 0; m < M; ++m) {
            float corr = fmaxf(qv[m] - qmin[m] + E_CONST, E_CONST);
            float phi  = (1.0f + w[m]) * corr + b[m];
            lphi[m] = logf(phi);
        }
        float modal[M];
        #pragma unroll
        for (int i = 0; i < M; ++i) {
            float s = 0.0f;
            #pragma unroll
            for (int j = 0; j < M; ++j) {
                float g = (i < j) ? gammas[i * M + j] : gammas[j * M + i];
                s += expf(fmaf(g, lphi[i] - lphi[j], lphi[j]));
            }
            modal[i] = s;
        }
        float mx = -modal[0];
        #pragma unroll
        for (int i = 1; i < M; ++i) mx = fmaxf(mx, -modal[i]);
        float esum = 0.0f;
        float ea[M];
        #pragma unroll
        for (int i = 0; i < M; ++i) { ea[i] = expf(-modal[i] - mx); esum += ea[i]; }
        float inv = 1.0f / esum;
        #pragma unroll
        for (int m = 0; m < M; ++m) {
            float t = tanhf(fmaf(G[m], ea[m] * inv, bias[m]));
            s_beta[tid][m] = fmaxf(t, 0.0f);
        }
    }
    __syncthreads();

    const size_t base = (size_t)row0 * (M * D);
    const float4* __restrict__ x4 = reinterpret_cast<const float4*>(x + base);
    float4* __restrict__ o4       = reinterpret_cast<float4*>(out + base);
    const int mm = tid >> 5;
    #pragma unroll 4
    for (int r = 0; r < ROWS_PER_BLOCK; ++r) {
        const float beta = s_beta[r][mm];
        float4 v = x4[(size_t)r * 256 + tid];
        v.x *= beta; v.y *= beta; v.z *= beta; v.w *= beta;
        o4[(size_t)r * 256 + tid] = v;
    }
}

extern "C" void kernel_launch(void* const* d_in, const int* in_sizes, int n_in,
                              void* d_out, int out_size, void* d_ws, size_t ws_size,
                              hipStream_t stream) {
    const float* x      = (const float*)d_in[0];
    const float* q      = (const float*)d_in[1];
    const float* w      = (const float*)d_in[2];
    const float* b      = (const float*)d_in[3];
    const float* gammas = (const float*)d_in[4];
    const float* G      = (const float*)d_in[5];
    const float* bias   = (const float*)d_in[6];
    const float* qmin   = (const float*)d_in[7];
    float* out = (float*)d_out;

    const size_t beta_bytes = (size_t)NROWS * M * sizeof(float);  // 4 MB
    if (ws_size >= beta_bytes) {
        float* betas = (float*)d_ws;
        emma_beta_kernel<<<NROWS / 256, 256, 0, stream>>>(
            q, w, b, gammas, G, bias, qmin, betas);
        emma_scale_kernel<<<SB_BLOCKS, 256, 0, stream>>>(
            (const float4*)x, betas, (float4*)out);
    } else {
        emma_fused_kernel<<<NROWS / ROWS_PER_BLOCK, 256, 0, stream>>>(
            x, q, w, b, gammas, G, bias, qmin, out);
    }
}

// Round 3
// 214.571 us; speedup vs baseline: 1.2166x; 1.2166x over previous
//
#include <hip/hip_runtime.h>
#include <math.h>

#define NROWS 131072
#define M 8
#define D 128
#define RPB 32   // rows per block; grid = 4096 blocks
#define E_CONST 2.71828182845904523536f

__global__ __launch_bounds__(256) void emma_fused2(
    const float* __restrict__ x, const float* __restrict__ q,
    const float* __restrict__ w, const float* __restrict__ b,
    const float* __restrict__ gammas, const float* __restrict__ G,
    const float* __restrict__ bias, const float* __restrict__ qmin,
    float* __restrict__ out)
{
    __shared__ float s_beta[RPB][M];

    const int tid = threadIdx.x;
    const int r   = tid >> 3;     // row within block (0..31)
    const int i   = tid & 7;      // mode this thread owns
    const int n   = blockIdx.x * RPB + r;

    // ---- Phase 1: 8 threads per row, one mode each. All 256 threads active.
    {
        const float4 q0 = *reinterpret_cast<const float4*>(q + (size_t)n * M);
        const float4 q1 = *reinterpret_cast<const float4*>(q + (size_t)n * M + 4);
        float qv[M] = {q0.x, q0.y, q0.z, q0.w, q1.x, q1.y, q1.z, q1.w};

        // lphi[m] = log(phi_m), phi >= e > 0.  (compile-time m only)
        float lphi[M];
        #pragma unroll
        for (int m = 0; m < M; ++m) {
            float corr = fmaxf(qv[m] - qmin[m] + E_CONST, E_CONST);
            float phi  = fmaf(w[m], corr, corr) + b[m];   // (1+w)*corr + b
            lphi[m] = logf(phi);
        }

        // select lphi[i] without dynamic register indexing (cndmask chain)
        float myl = lphi[0];
        #pragma unroll
        for (int m = 1; m < M; ++m) if (i == m) myl = lphi[m];

        // modal_i = sum_j exp(g_sym[i][j]*(lphi_i - lphi_j) + lphi_j)
        float s = 0.0f;
        #pragma unroll
        for (int j = 0; j < M; ++j) {
            int lo = (i < j) ? i : j;
            int hi = (i < j) ? j : i;
            float g = gammas[lo * M + hi];     // 256 B table, L1-resident
            s += expf(fmaf(g, myl - lphi[j], lphi[j]));
        }

        // softmax over the 8 modes of this row (lanes r*8 .. r*8+7)
        float neg = -s;                         // TAU = 1
        float mx = neg;
        #pragma unroll
        for (int d = 1; d < 8; d <<= 1) mx = fmaxf(mx, __shfl_xor(mx, d, 8));
        float e = expf(neg - mx);
        float sum = e;
        #pragma unroll
        for (int d = 1; d < 8; d <<= 1) sum += __shfl_xor(sum, d, 8);
        float alpha = e / sum;

        float t = tanhf(fmaf(G[i], alpha, bias[i]));
        s_beta[r][i] = fmaxf(t, 0.0f);          // consecutive addrs: conflict-free
    }
    __syncthreads();

    // ---- Phase 2: stream 32 rows x 256 float4, perfectly coalesced.
    const size_t base = (size_t)blockIdx.x * (RPB * M * D);
    const float4* __restrict__ x4 = reinterpret_cast<const float4*>(x + base);
    float4* __restrict__ o4       = reinterpret_cast<float4*>(out + base);
    const int mm = tid >> 5;   // mode of this thread's float4 (LDS broadcast)

    #pragma unroll 4
    for (int rr = 0; rr < RPB; ++rr) {
        const float beta = s_beta[rr][mm];
        float4 v = x4[(size_t)rr * 256 + tid];
        v.x *= beta; v.y *= beta; v.z *= beta; v.w *= beta;
        o4[(size_t)rr * 256 + tid] = v;
    }
}

extern "C" void kernel_launch(void* const* d_in, const int* in_sizes, int n_in,
                              void* d_out, int out_size, void* d_ws, size_t ws_size,
                              hipStream_t stream) {
    const float* x      = (const float*)d_in[0];
    const float* q      = (const float*)d_in[1];
    const float* w      = (const float*)d_in[2];
    const float* b      = (const float*)d_in[3];
    const float* gammas = (const float*)d_in[4];
    const float* G      = (const float*)d_in[5];
    const float* bias   = (const float*)d_in[6];
    const float* qmin   = (const float*)d_in[7];
    float* out = (float*)d_out;

    emma_fused2<<<NROWS / RPB, 256, 0, stream>>>(
        x, q, w, b, gammas, G, bias, qmin, out);
}

// Round 4
// 189.525 us; speedup vs baseline: 1.3774x; 1.1321x over previous
//
#include <hip/hip_runtime.h>
#include <math.h>

#define NROWS 131072
#define M 8
#define D 128
#define RPB 32   // rows per block; grid = 4096 blocks
#define E_CONST 2.71828182845904523536f

typedef float f32x4 __attribute__((ext_vector_type(4)));

__global__ __launch_bounds__(256) void emma_fused3(
    const float* __restrict__ x, const float* __restrict__ q,
    const float* __restrict__ w, const float* __restrict__ b,
    const float* __restrict__ gammas, const float* __restrict__ G,
    const float* __restrict__ bias, const float* __restrict__ qmin,
    float* __restrict__ out)
{
    __shared__ float s_beta[RPB][M];

    const int tid = threadIdx.x;
    const int r   = tid >> 3;     // row within block (0..31)
    const int i   = tid & 7;      // mode this thread owns
    const int n   = blockIdx.x * RPB + r;

    // ---- Phase 1: 8 threads per row, one mode each. (~6 us aggregate)
    {
        const f32x4 q0 = *reinterpret_cast<const f32x4*>(q + (size_t)n * M);
        const f32x4 q1 = *reinterpret_cast<const f32x4*>(q + (size_t)n * M + 4);
        float qv[M] = {q0.x, q0.y, q0.z, q0.w, q1.x, q1.y, q1.z, q1.w};

        float lphi[M];
        #pragma unroll
        for (int m = 0; m < M; ++m) {
            float corr = fmaxf(qv[m] - qmin[m] + E_CONST, E_CONST);
            float phi  = fmaf(w[m], corr, corr) + b[m];   // (1+w)*corr + b
            lphi[m] = logf(phi);                           // phi >= e > 0
        }

        // lphi[i] without dynamic register indexing
        float myl = lphi[0];
        #pragma unroll
        for (int m = 1; m < M; ++m) if (i == m) myl = lphi[m];

        // modal_i = sum_j exp(g_sym[i][j]*(lphi_i - lphi_j) + lphi_j)
        float s = 0.0f;
        #pragma unroll
        for (int j = 0; j < M; ++j) {
            int lo = (i < j) ? i : j;
            int hi = (i < j) ? j : i;
            float g = gammas[lo * M + hi];     // 256 B table, cache-resident
            s += expf(fmaf(g, myl - lphi[j], lphi[j]));
        }

        // softmax over the 8 modes of this row (TAU = 1)
        float neg = -s;
        float mx = neg;
        #pragma unroll
        for (int d = 1; d < 8; d <<= 1) mx = fmaxf(mx, __shfl_xor(mx, d, 8));
        float e = expf(neg - mx);
        float sum = e;
        #pragma unroll
        for (int d = 1; d < 8; d <<= 1) sum += __shfl_xor(sum, d, 8);
        float alpha = e / sum;

        float t = tanhf(fmaf(G[i], alpha, bias[i]));
        s_beta[r][i] = fmaxf(t, 0.0f);
    }
    __syncthreads();

    // ---- Phase 2: nontemporal streaming, 8 loads in flight before 8 stores.
    const size_t base = (size_t)blockIdx.x * (RPB * M * D);
    const f32x4* __restrict__ x4 = reinterpret_cast<const f32x4*>(x + base);
    f32x4* __restrict__ o4       = reinterpret_cast<f32x4*>(out + base);
    const int mm = tid >> 5;   // mode of this thread's float4 column

    #pragma unroll
    for (int g = 0; g < RPB / 8; ++g) {      // 4 groups of 8 rows
        f32x4 v[8];
        float bb[8];
        #pragma unroll
        for (int u = 0; u < 8; ++u) {
            const int rr = g * 8 + u;
            v[u]  = __builtin_nontemporal_load(&x4[(size_t)rr * 256 + tid]);
            bb[u] = s_beta[rr][mm];
        }
        #pragma unroll
        for (int u = 0; u < 8; ++u) {
            const int rr = g * 8 + u;
            f32x4 t = v[u] * bb[u];
            __builtin_nontemporal_store(t, &o4[(size_t)rr * 256 + tid]);
        }
    }
}

extern "C" void kernel_launch(void* const* d_in, const int* in_sizes, int n_in,
                              void* d_out, int out_size, void* d_ws, size_t ws_size,
                              hipStream_t stream) {
    const float* x      = (const float*)d_in[0];
    const float* q      = (const float*)d_in[1];
    const float* w      = (const float*)d_in[2];
    const float* b      = (const float*)d_in[3];
    const float* gammas = (const float*)d_in[4];
    const float* G      = (const float*)d_in[5];
    const float* bias   = (const float*)d_in[6];
    const float* qmin   = (const float*)d_in[7];
    float* out = (float*)d_out;

    emma_fused3<<<NROWS / RPB, 256, 0, stream>>>(
        x, q, w, b, gammas, G, bias, qmin, out);
}

// Round 5
// 189.379 us; speedup vs baseline: 1.3784x; 1.0008x over previous
//
#include <hip/hip_runtime.h>
#include <math.h>

#define NROWS 131072
#define M 8
#define D 128
#define RPB 32   // rows per block; grid = 4096 blocks
#define E_CONST 2.71828182845904523536f

typedef float f32x4 __attribute__((ext_vector_type(4)));

__global__ __launch_bounds__(256) void emma_fused4(
    const float* __restrict__ x, const float* __restrict__ q,
    const float* __restrict__ w, const float* __restrict__ b,
    const float* __restrict__ gammas, const float* __restrict__ G,
    const float* __restrict__ bias, const float* __restrict__ qmin,
    float* __restrict__ out)
{
    __shared__ float s_beta[RPB][M];

    const int tid = threadIdx.x;
    const int r   = tid >> 3;     // row within block (0..31)
    const int i   = tid & 7;      // mode this thread owns
    const int n   = blockIdx.x * RPB + r;

    const size_t base = (size_t)blockIdx.x * (RPB * M * D);
    const f32x4* __restrict__ x4 = reinterpret_cast<const f32x4*>(x + base);
    f32x4* __restrict__ o4       = reinterpret_cast<f32x4*>(out + base);
    const int mm = tid >> 5;      // mode of this thread's float4 column

    // ---- Prologue: issue group-0 loads BEFORE phase-1 (independent of betas).
    f32x4 vA[8], vB[8];
    #pragma unroll
    for (int u = 0; u < 8; ++u)
        vA[u] = __builtin_nontemporal_load(&x4[(size_t)u * 256 + tid]);

    // ---- Phase 1: 8 threads per row, one mode each. Hidden under vA loads.
    {
        const f32x4 q0 = *reinterpret_cast<const f32x4*>(q + (size_t)n * M);
        const f32x4 q1 = *reinterpret_cast<const f32x4*>(q + (size_t)n * M + 4);
        float qv[M] = {q0.x, q0.y, q0.z, q0.w, q1.x, q1.y, q1.z, q1.w};

        float lphi[M];
        #pragma unroll
        for (int m = 0; m < M; ++m) {
            float corr = fmaxf(qv[m] - qmin[m] + E_CONST, E_CONST);
            float phi  = fmaf(w[m], corr, corr) + b[m];   // (1+w)*corr + b
            lphi[m] = logf(phi);                           // phi >= e > 0
        }

        float myl = lphi[0];
        #pragma unroll
        for (int m = 1; m < M; ++m) if (i == m) myl = lphi[m];

        float s = 0.0f;
        #pragma unroll
        for (int j = 0; j < M; ++j) {
            int lo = (i < j) ? i : j;
            int hi = (i < j) ? j : i;
            float g = gammas[lo * M + hi];
            s += expf(fmaf(g, myl - lphi[j], lphi[j]));
        }

        float neg = -s;                                    // TAU = 1
        float mx = neg;
        #pragma unroll
        for (int d = 1; d < 8; d <<= 1) mx = fmaxf(mx, __shfl_xor(mx, d, 8));
        float e = expf(neg - mx);
        float sum = e;
        #pragma unroll
        for (int d = 1; d < 8; d <<= 1) sum += __shfl_xor(sum, d, 8);
        float alpha = e / sum;

        float t = tanhf(fmaf(G[i], alpha, bias[i]));
        s_beta[r][i] = fmaxf(t, 0.0f);
    }
    __syncthreads();

    // ---- Phase 2: software-pipelined: prefetch group g+1, process group g.
    // Named buffers, fully static indexing (no runtime-indexed arrays).
#define PREFETCH(BUF, G_)                                                     \
    _Pragma("unroll")                                                         \
    for (int u = 0; u < 8; ++u)                                               \
        BUF[u] = __builtin_nontemporal_load(                                  \
            &x4[(size_t)((G_) * 8 + u) * 256 + tid]);

#define PROCESS(BUF, G_)                                                      \
    _Pragma("unroll")                                                         \
    for (int u = 0; u < 8; ++u) {                                             \
        const int rr = (G_) * 8 + u;                                          \
        f32x4 t = BUF[u] * s_beta[rr][mm];                                    \
        __builtin_nontemporal_store(t, &o4[(size_t)rr * 256 + tid]);          \
    }

    PREFETCH(vB, 1)
    PROCESS(vA, 0)
    PREFETCH(vA, 2)
    PROCESS(vB, 1)
    PREFETCH(vB, 3)
    PROCESS(vA, 2)
    PROCESS(vB, 3)

#undef PREFETCH
#undef PROCESS
}

extern "C" void kernel_launch(void* const* d_in, const int* in_sizes, int n_in,
                              void* d_out, int out_size, void* d_ws, size_t ws_size,
                              hipStream_t stream) {
    const float* x      = (const float*)d_in[0];
    const float* q      = (const float*)d_in[1];
    const float* w      = (const float*)d_in[2];
    const float* b      = (const float*)d_in[3];
    const float* gammas = (const float*)d_in[4];
    const float* G      = (const float*)d_in[5];
    const float* bias   = (const float*)d_in[6];
    const float* qmin   = (const float*)d_in[7];
    float* out = (float*)d_out;

    emma_fused4<<<NROWS / RPB, 256, 0, stream>>>(
        x, q, w, b, gammas, G, bias, qmin, out);
}

// Round 6
// 186.363 us; speedup vs baseline: 1.4008x; 1.0162x over previous
//
#include <hip/hip_runtime.h>
#include <math.h>

#define NROWS 131072
#define M 8
#define D 128
#define RPB 32   // rows per block; grid = 4096 blocks
#define E_CONST 2.71828182845904523536f

typedef float f32x4 __attribute__((ext_vector_type(4)));

__global__ __launch_bounds__(256) void emma_fused5(
    const float* __restrict__ x, const float* __restrict__ q,
    const float* __restrict__ w, const float* __restrict__ b,
    const float* __restrict__ gammas, const float* __restrict__ G,
    const float* __restrict__ bias, const float* __restrict__ qmin,
    float* __restrict__ out)
{
    __shared__ float s_beta[RPB][M];

    const int tid = threadIdx.x;
    const int r   = tid >> 3;     // row within block (0..31)
    const int i   = tid & 7;      // mode this thread owns
    const int n   = blockIdx.x * RPB + r;

    const size_t base = (size_t)blockIdx.x * (RPB * M * D);
    const f32x4* __restrict__ x4 = reinterpret_cast<const f32x4*>(x + base);
    f32x4* __restrict__ o4       = reinterpret_cast<f32x4*>(out + base);
    const int mm = tid >> 5;      // mode of this thread's float4 column

    // ---- Phase 1: 8 threads per row, one mode each (~6 us aggregate).
    {
        const f32x4 q0 = *reinterpret_cast<const f32x4*>(q + (size_t)n * M);
        const f32x4 q1 = *reinterpret_cast<const f32x4*>(q + (size_t)n * M + 4);
        float qv[M] = {q0.x, q0.y, q0.z, q0.w, q1.x, q1.y, q1.z, q1.w};

        float lphi[M];
        #pragma unroll
        for (int m = 0; m < M; ++m) {
            float corr = fmaxf(qv[m] - qmin[m] + E_CONST, E_CONST);
            float phi  = fmaf(w[m], corr, corr) + b[m];   // (1+w)*corr + b
            lphi[m] = logf(phi);                           // phi >= e > 0
        }

        float myl = lphi[0];
        #pragma unroll
        for (int m = 1; m < M; ++m) if (i == m) myl = lphi[m];

        float s = 0.0f;
        #pragma unroll
        for (int j = 0; j < M; ++j) {
            int lo = (i < j) ? i : j;
            int hi = (i < j) ? j : i;
            float g = gammas[lo * M + hi];
            s += expf(fmaf(g, myl - lphi[j], lphi[j]));
        }

        float neg = -s;                                    // TAU = 1
        float mx = neg;
        #pragma unroll
        for (int d = 1; d < 8; d <<= 1) mx = fmaxf(mx, __shfl_xor(mx, d, 8));
        float e = expf(neg - mx);
        float sum = e;
        #pragma unroll
        for (int d = 1; d < 8; d <<= 1) sum += __shfl_xor(sum, d, 8);
        float alpha = e / sum;

        float t = tanhf(fmaf(G[i], alpha, bias[i]));
        s_beta[r][i] = fmaxf(t, 0.0f);
    }
    __syncthreads();

    // ---- Phase 2: pipelined nontemporal streaming with zero-beta load skip.
    // beta == 0.0f exactly => out row-segment is exactly 0*x = 0: skip the
    // x read (exec-masked lanes issue no memory requests), still store.
    f32x4 vA[8], vB[8];
    const f32x4 zero4 = {0.f, 0.f, 0.f, 0.f};

#define PREFETCH(BUF, G_)                                                     \
    _Pragma("unroll")                                                         \
    for (int u = 0; u < 8; ++u) {                                             \
        const int rr = (G_) * 8 + u;                                          \
        const float bb = s_beta[rr][mm];                                      \
        BUF[u] = (bb != 0.0f)                                                 \
            ? __builtin_nontemporal_load(&x4[(size_t)rr * 256 + tid])         \
            : zero4;                                                          \
    }

#define PROCESS(BUF, G_)                                                      \
    _Pragma("unroll")                                                         \
    for (int u = 0; u < 8; ++u) {                                             \
        const int rr = (G_) * 8 + u;                                          \
        f32x4 t = BUF[u] * s_beta[rr][mm];                                    \
        __builtin_nontemporal_store(t, &o4[(size_t)rr * 256 + tid]);          \
    }

    PREFETCH(vA, 0)
    PREFETCH(vB, 1)
    PROCESS(vA, 0)
    PREFETCH(vA, 2)
    PROCESS(vB, 1)
    PREFETCH(vB, 3)
    PROCESS(vA, 2)
    PROCESS(vB, 3)

#undef PREFETCH
#undef PROCESS
}

extern "C" void kernel_launch(void* const* d_in, const int* in_sizes, int n_in,
                              void* d_out, int out_size, void* d_ws, size_t ws_size,
                              hipStream_t stream) {
    const float* x      = (const float*)d_in[0];
    const float* q      = (const float*)d_in[1];
    const float* w      = (const float*)d_in[2];
    const float* b      = (const float*)d_in[3];
    const float* gammas = (const float*)d_in[4];
    const float* G      = (const float*)d_in[5];
    const float* bias   = (const float*)d_in[6];
    const float* qmin   = (const float*)d_in[7];
    float* out = (float*)d_out;

    emma_fused5<<<NROWS / RPB, 256, 0, stream>>>(
        x, q, w, b, gammas, G, bias, qmin, out);
}